// Round 13
// baseline (2033.060 us; speedup 1.0000x reference)
//
#include <hip/hip_runtime.h>
#include <hip/hip_bf16.h>

// Problem constants (match reference).
#define VOCAB  50257
#define D_EMB  128
#define HID    256
#define N_CLS  2
#define BSZ    256
#define T_LEN  2048

typedef __attribute__((ext_vector_type(8))) short s8v;   // 8 bf16 (4 VGPR)
typedef __attribute__((ext_vector_type(4))) float f4v;   // 4 f32  (4 VGPR)

// ---------------------------------------------------------------------------
// Kernel 1: tab[v][j] = sum_d emb_table[v][d] * wx_w[d][j] + wx_b[j] + wh_b[j]
// ---------------------------------------------------------------------------
__global__ __launch_bounds__(256)
void tabax_kernel(const float* __restrict__ emb,
                  const float* __restrict__ wxw,
                  const float* __restrict__ wxb,
                  const float* __restrict__ whb,
                  float* __restrict__ tab)
{
    const int j  = threadIdx.x;          // output unit 0..255
    const int v0 = blockIdx.x * 32;
    const int rows = min(32, VOCAB - v0);

    __shared__ float ebuf[32 * D_EMB];   // 16 KB
    for (int i = j; i < rows * D_EMB; i += 256)
        ebuf[i] = emb[(size_t)v0 * D_EMB + i];
    __syncthreads();

    float acc[32];
#pragma unroll
    for (int r = 0; r < 32; ++r) acc[r] = 0.f;

#pragma unroll 8
    for (int d = 0; d < D_EMB; ++d) {
        float wxv = wxw[d * HID + j];    // coalesced
#pragma unroll
        for (int r = 0; r < 32; ++r)
            acc[r] = fmaf(ebuf[r * D_EMB + d], wxv, acc[r]); // LDS broadcast
    }

    const float bb = wxb[j] + whb[j];
    for (int r = 0; r < rows; ++r)
        tab[(size_t)(v0 + r) * HID + j] = acc[r] + bb;       // coalesced
}

__device__ __forceinline__ float fast_tanh(float x) {
    float e2 = __expf(2.f * x);
    return 1.f - 2.f / (e2 + 1.f);
}

// Split f32 into bf16 hi + bf16 lo (truncating): x ~= hi + lo with residual
// <= 2^-16 |x|. Products of two splits computed exactly in MFMA (bf16xbf16
// exact in f32), so 3-product matvec error ~2^-16 per step.
__device__ __forceinline__ void split_bf16(float x, unsigned short& hi,
                                           unsigned short& lo) {
    unsigned int u = __float_as_uint(x);
    hi = (unsigned short)(u >> 16);
    float hif = __uint_as_float(u & 0xFFFF0000u);
    float r = x - hif;
    lo = (unsigned short)(__float_as_uint(r) >> 16);
}

// ---------------------------------------------------------------------------
// Kernel 2 (main): one block per batch row, 1024 threads = 16 waves.
// The recurrent matvec y = h @ Whh runs on MFMA (16x16x32 bf16):
//   - Wave w owns output cols [16w, 16w+16). B-frags = Whh[k][16 cols] as
//     bf16 HI and LO (8 k-slices x 2 x 4 VGPR = 64 regs, loaded ONCE).
//     MFMA reads A/B from AGPRs natively, so if the RA stashes them in
//     AGPRs (as it did for 5 rounds of VALU kernels) it is now FREE.
//   - h lives in LDS as bf16 hi/lo; A-frags are 16-way-broadcast
//     ds_read_b128 (every lane reads h[k-slice] -> all 16 MFMA rows hold
//     the same duplicated row; rows are independent so the redundancy is
//     harmless and C is row-duplicated).
//   - 3 products per step: c1=Ahi*Bhi, c2=Ahi*Blo, c3=Alo*Bhi (lo*lo term
//     ~8e-6/step, dropped). x = c1+c2+c3 + ax; h' = tanh(x); split -> LDS.
// C/D layout (m89-verified): col=lane&15, row=(lane>>4)*4+reg. Lanes 0-15,
// reg 0 = row 0 = our 16 cols.
// Per block-step: 384 MFMA = 96/SIMD ~ 466 cyc; VALU epilogue co-issues.
// ---------------------------------------------------------------------------
__global__ __launch_bounds__(1024, 1)
void rnn_main_kernel(const int*   __restrict__ batch,
                     const float* __restrict__ whw,
                     const float* __restrict__ clfw,
                     const float* __restrict__ clfb,
                     const float* __restrict__ ax_tab,
                     float*       __restrict__ out)
{
    const int b    = blockIdx.x;
    const int tid  = threadIdx.x;
    const int wave = tid >> 6;           // 0..15: owns cols [wave*16, +16)
    const int lane = tid & 63;
    const int lq   = lane >> 4;          // k-subgroup 0..3
    const int lc   = lane & 15;          // col within tile / B col index

    __shared__ unsigned short hh[2][HID];   // h hi (bf16 bits), dbl-buffered
    __shared__ unsigned short hl[2][HID];   // h lo
    __shared__ float sbuf[2][HID];          // epilogue scratch

    // --- one-time B-fragment build: W[k][wave*16+lc], k = s*32 + lq*8 + j ---
    s8v bhi[8], blo[8];
#pragma unroll
    for (int s = 0; s < 8; ++s) {
#pragma unroll
        for (int j = 0; j < 8; ++j) {
            const int k = s * 32 + lq * 8 + j;
            const float w = whw[(size_t)k * HID + wave * 16 + lc];
            unsigned short hi, lo;
            split_bf16(w, hi, lo);
            bhi[s][j] = (short)hi;
            blo[s][j] = (short)lo;
        }
    }

    const int mycolax = wave * 16 + lc;  // ax column this lane uses

    if (tid < HID) { hh[0][tid] = 0; hl[0][tid] = 0; }   // h(t=0) = 0

    const int* brow = batch + (size_t)b * T_LEN;
    int tok_n = brow[0];
    float axv = ax_tab[(size_t)tok_n * HID + mycolax];   // ax for t=0
    tok_n = brow[1];
    __syncthreads();

#define RNN_STEP(CUR, NXT, TT)                                              \
    {                                                                       \
        const int tok_nn = ((TT) + 2 < T_LEN) ? brow[(TT) + 2] : 0;         \
        const float ax_n = ax_tab[(size_t)tok_n * HID + mycolax];           \
        f4v c1 = {0.f, 0.f, 0.f, 0.f};                                      \
        f4v c2 = {0.f, 0.f, 0.f, 0.f};                                      \
        f4v c3 = {0.f, 0.f, 0.f, 0.f};                                      \
        _Pragma("unroll")                                                   \
        for (int s = 0; s < 8; ++s) {                                       \
            const s8v ahi = *(const s8v*)&hh[CUR][s * 32 + lq * 8];         \
            const s8v alo = *(const s8v*)&hl[CUR][s * 32 + lq * 8];         \
            c1 = __builtin_amdgcn_mfma_f32_16x16x32_bf16(ahi, bhi[s], c1,   \
                                                         0, 0, 0);          \
            c2 = __builtin_amdgcn_mfma_f32_16x16x32_bf16(ahi, blo[s], c2,   \
                                                         0, 0, 0);          \
            c3 = __builtin_amdgcn_mfma_f32_16x16x32_bf16(alo, bhi[s], c3,   \
                                                         0, 0, 0);          \
        }                                                                   \
        const float x  = (c1[0] + c2[0]) + c3[0] + axv;                     \
        const float hn = fast_tanh(x);                                      \
        unsigned short hi_, lo_;                                            \
        split_bf16(hn, hi_, lo_);                                           \
        if (lane < 16) {   /* row 0 lanes: col = wave*16 + lane */          \
            hh[NXT][wave * 16 + lane] = hi_;                                \
            hl[NXT][wave * 16 + lane] = lo_;                                \
        }                                                                   \
        __syncthreads();                                                    \
        axv   = ax_n;                                                       \
        tok_n = tok_nn;                                                     \
    }

    for (int t = 0; t < T_LEN; t += 2) {
        RNN_STEP(0, 1, t)
        RNN_STEP(1, 0, t + 1)
    }
#undef RNN_STEP

    // --- epilogue: out[b][c] = sum_j h[j] * clf_w[j][c] + clf_b[c] ---
    // After an even number of steps the final h is in buffer 0.
    if (tid < HID) {
        const float h = __uint_as_float(((unsigned int)hh[0][tid]) << 16) +
                        __uint_as_float(((unsigned int)hl[0][tid]) << 16);
        sbuf[0][tid] = h * clfw[tid * N_CLS + 0];
        sbuf[1][tid] = h * clfw[tid * N_CLS + 1];
    }
    __syncthreads();
    if (tid < 64) {
        float v = sbuf[0][tid] + sbuf[0][tid + 64] +
                  sbuf[0][tid + 128] + sbuf[0][tid + 192];
#pragma unroll
        for (int off = 32; off > 0; off >>= 1) v += __shfl_xor(v, off);
        if (tid == 0) out[b * N_CLS + 0] = v + clfb[0];
    } else if (tid < 128) {
        const int l = tid - 64;
        float v = sbuf[1][l] + sbuf[1][l + 64] +
                  sbuf[1][l + 128] + sbuf[1][l + 192];
#pragma unroll
        for (int off = 32; off > 0; off >>= 1) v += __shfl_xor(v, off);
        if (l == 0) out[b * N_CLS + 1] = v + clfb[1];
    }
}

// ---------------------------------------------------------------------------
// Fallback (workspace too small for the 51.5 MB table).
// ---------------------------------------------------------------------------
__global__ __launch_bounds__(512, 2)
void rnn_fallback_kernel(const int*   __restrict__ batch,
                         const float* __restrict__ emb,
                         const float* __restrict__ wxw,
                         const float* __restrict__ wxb,
                         const float* __restrict__ whw,
                         const float* __restrict__ whb,
                         const float* __restrict__ clfw,
                         const float* __restrict__ clfb,
                         float*       __restrict__ out)
{
    const int b    = blockIdx.x;
    const int tid  = threadIdx.x;
    const int j    = tid >> 1;
    const int half = tid & 1;
    const int k0   = half * 128;

    __shared__ float hbuf[2][HID];
    __shared__ float ebuf[2][D_EMB];

    float w[128];
#pragma unroll
    for (int k = 0; k < 128; ++k)
        w[k] = whw[(size_t)(k0 + k) * HID + j];

    float wx[64];
#pragma unroll
    for (int d = 0; d < 64; ++d)
        wx[d] = wxw[(size_t)(half * 64 + d) * HID + j];

    const float bj  = whb[j];
    const float axb = wxb[j];

    if (tid < HID) hbuf[0][tid] = 0.f;

    const int* brow = batch + (size_t)b * T_LEN;

    int tok_n = brow[0];
    if (tid < D_EMB) ebuf[0][tid] = emb[(size_t)tok_n * D_EMB + tid];
    tok_n = brow[1];
    __syncthreads();

    float h_j = 0.f;
    int cur = 0;
    for (int t = 0; t < T_LEN; ++t) {
        const int nxt = cur ^ 1;
        const int tok_nn = (t + 2 < T_LEN) ? brow[t + 2] : 0;
        float ev = 0.f;
        if (t + 1 < T_LEN && tid < D_EMB)
            ev = emb[(size_t)tok_n * D_EMB + tid];

        float a0 = 0.f, a1 = 0.f, a2 = 0.f, a3 = 0.f;
        const float4* hv = (const float4*)&hbuf[cur][k0];
#pragma unroll
        for (int i = 0; i < 32; ++i) {
            float4 h4 = hv[i];
            a0 = fmaf(h4.x, w[4 * i + 0], a0);
            a1 = fmaf(h4.y, w[4 * i + 1], a1);
            a2 = fmaf(h4.z, w[4 * i + 2], a2);
            a3 = fmaf(h4.w, w[4 * i + 3], a3);
        }
        const float4* evv = (const float4*)&ebuf[cur][half * 64];
#pragma unroll
        for (int i = 0; i < 16; ++i) {
            float4 e4 = evv[i];
            a0 = fmaf(e4.x, wx[4 * i + 0], a0);
            a1 = fmaf(e4.y, wx[4 * i + 1], a1);
            a2 = fmaf(e4.z, wx[4 * i + 2], a2);
            a3 = fmaf(e4.w, wx[4 * i + 3], a3);
        }
        float s = (a0 + a1) + (a2 + a3);
        s += __shfl_xor(s, 1);

        h_j = fast_tanh(s + bj + axb);

        if (half == 0) hbuf[nxt][j] = h_j;
        if (t + 1 < T_LEN && tid < D_EMB) ebuf[nxt][tid] = ev;
        __syncthreads();

        tok_n = tok_nn;
        cur   = nxt;
    }

    if (half == 0) {
        hbuf[0][j] = h_j * clfw[j * N_CLS + 0];
        hbuf[1][j] = h_j * clfw[j * N_CLS + 1];
    }
    __syncthreads();
    if (tid < 64) {
        float v = hbuf[0][tid] + hbuf[0][tid + 64] +
                  hbuf[0][tid + 128] + hbuf[0][tid + 192];
#pragma unroll
        for (int off = 32; off > 0; off >>= 1) v += __shfl_xor(v, off);
        if (tid == 0) out[b * N_CLS + 0] = v + clfb[0];
    } else if (tid < 128) {
        const int l = tid - 64;
        float v = hbuf[1][l] + hbuf[1][l + 64] +
                  hbuf[1][l + 128] + hbuf[1][l + 192];
#pragma unroll
        for (int off = 32; off > 0; off >>= 1) v += __shfl_xor(v, off);
        if (l == 0) out[b * N_CLS + 1] = v + clfb[1];
    }
}

// ---------------------------------------------------------------------------
extern "C" void kernel_launch(void* const* d_in, const int* in_sizes, int n_in,
                              void* d_out, int out_size, void* d_ws, size_t ws_size,
                              hipStream_t stream)
{
    const int*   batch = (const int*)  d_in[0];
    const float* emb   = (const float*)d_in[1];
    const float* wxw   = (const float*)d_in[2];
    const float* wxb   = (const float*)d_in[3];
    const float* whw   = (const float*)d_in[4];
    const float* whb   = (const float*)d_in[5];
    const float* clfw  = (const float*)d_in[6];
    const float* clfb  = (const float*)d_in[7];
    float* out = (float*)d_out;

    const size_t tab_bytes = (size_t)VOCAB * HID * sizeof(float);
    if (ws_size >= tab_bytes) {
        float* tab = (float*)d_ws;
        tabax_kernel<<<(VOCAB + 31) / 32, 256, 0, stream>>>(emb, wxw, wxb, whb, tab);
        rnn_main_kernel<<<BSZ, 1024, 0, stream>>>(batch, whw, clfw, clfb, tab, out);
    } else {
        rnn_fallback_kernel<<<BSZ, 512, 0, stream>>>(batch, emb, wxw, wxb, whw, whb,
                                                     clfw, clfb, out);
    }
}

// Round 14
// 1748.267 us; speedup vs baseline: 1.1629x; 1.1629x over previous
//
#include <hip/hip_runtime.h>
#include <hip/hip_bf16.h>

// Problem constants (match reference).
#define VOCAB  50257
#define D_EMB  128
#define HID    256
#define N_CLS  2
#define BSZ    256
#define T_LEN  2048

// ---------------------------------------------------------------------------
// Kernel 1: tab[v][j] = sum_d emb_table[v][d] * wx_w[d][j] + wx_b[j] + wh_b[j]
// ---------------------------------------------------------------------------
__global__ __launch_bounds__(256)
void tabax_kernel(const float* __restrict__ emb,
                  const float* __restrict__ wxw,
                  const float* __restrict__ wxb,
                  const float* __restrict__ whb,
                  float* __restrict__ tab)
{
    const int j  = threadIdx.x;          // output unit 0..255
    const int v0 = blockIdx.x * 32;
    const int rows = min(32, VOCAB - v0);

    __shared__ float ebuf[32 * D_EMB];   // 16 KB
    for (int i = j; i < rows * D_EMB; i += 256)
        ebuf[i] = emb[(size_t)v0 * D_EMB + i];
    __syncthreads();

    float acc[32];
#pragma unroll
    for (int r = 0; r < 32; ++r) acc[r] = 0.f;

#pragma unroll 8
    for (int d = 0; d < D_EMB; ++d) {
        float wxv = wxw[d * HID + j];    // coalesced
#pragma unroll
        for (int r = 0; r < 32; ++r)
            acc[r] = fmaf(ebuf[r * D_EMB + d], wxv, acc[r]); // LDS broadcast
    }

    const float bb = wxb[j] + whb[j];
    for (int r = 0; r < rows; ++r)
        tab[(size_t)(v0 + r) * HID + j] = acc[r] + bb;       // coalesced
}

__device__ __forceinline__ float fast_tanh(float x) {
    float e2 = __expf(2.f * x);
    return 1.f - 2.f / (e2 + 1.f);
}

// Packed dual-f32 FMA (CDNA double-rate fp32; why MI355X vector f32 = 157 TF
// = 2x the scalar v_fma rate). op_sel broadcasts one 32-bit half of the h
// pair to BOTH lanes of the product -- no duplicated storage, no extra movs.
//   PK lo-broadcast: lo: h.lo*w.lo + a.lo ; hi: h.lo*w.hi + a.hi
//   PK hi-broadcast: lo: h.hi*w.lo + a.lo ; hi: h.hi*w.hi + a.hi
#define PKFMA_LO(ACC, H2, W2)                                               \
    asm("v_pk_fma_f32 %0, %1, %2, %0 op_sel:[0,0,0] op_sel_hi:[0,1,1]"      \
        : "+v"(ACC) : "v"(H2), "v"(W2))
#define PKFMA_HI(ACC, H2, W2)                                               \
    asm("v_pk_fma_f32 %0, %1, %2, %0 op_sel:[1,0,0] op_sel_hi:[1,1,1]"      \
        : "+v"(ACC) : "v"(H2), "v"(W2))
#define PKMUL_LO(ACC, H2, W2)                                               \
    asm("v_pk_mul_f32 %0, %1, %2 op_sel:[0,0] op_sel_hi:[0,1]"              \
        : "=v"(ACC) : "v"(H2), "v"(W2))

// ---------------------------------------------------------------------------
// Kernel 2 (main): one block per batch row, 1024 threads (16 waves, 4/SIMD).
// Identical structure to the 1556us R11 kernel (tiling, swizzle, tree,
// prefetch) with ONE change: the 64 scalar FMAs per thread become 32
// v_pk_fma_f32 (2 MACs/instruction), halving the mandatory VALU issue.
// Thread (cg = tid>>4, kg = tid&15) owns cols [cg*4, cg*4+4) over k in
// [kg*16, kg*16+16); weights as 32 float2 Wp[e][m][{cols01,cols23}].
// Bank swizzle rot=(kg>>2)&3: 2 addrs per bank-quad = conflict-free
// (0 conflicts measured R7-R12).
// ---------------------------------------------------------------------------
__global__ __launch_bounds__(1024, 1)
void rnn_main_kernel(const int*   __restrict__ batch,
                     const float* __restrict__ whw,
                     const float* __restrict__ clfw,
                     const float* __restrict__ clfb,
                     const float* __restrict__ ax_tab,
                     float*       __restrict__ out)
{
    const int b   = blockIdx.x;
    const int tid = threadIdx.x;
    const int kg  = tid & 15;            // k-group: k in [kg*16, kg*16+16)
    const int cg  = tid >> 4;            // col-group: cols [cg*4, cg*4+4)
    const int c0  = cg * 4;
    const int kb  = kg * 16;
    const int rot = (kg >> 2) & 3;       // bank-swizzle rotation

    __shared__ float hbuf[2][HID];       // double-buffered hidden state
    __shared__ float sbuf[2][HID];       // epilogue scratch

    // --- one-time weight load: rows k = kb + ((e+rot)&3)*4 + m, cols c0.. ---
    float2 Wp[4][4][2];                  // [e][m][cols01 | cols23]
#pragma unroll
    for (int e = 0; e < 4; ++e) {
        const int swz = (e + rot) & 3;
#pragma unroll
        for (int m = 0; m < 4; ++m) {
            const int k = kb + swz * 4 + m;
            const float4 w4 = *(const float4*)&whw[(size_t)k * HID + c0];
            Wp[e][m][0] = make_float2(w4.x, w4.y);
            Wp[e][m][1] = make_float2(w4.z, w4.w);
        }
    }
    // Pin once: asm redefines each pair -> loads cannot be rematerialized.
#pragma unroll
    for (int e = 0; e < 4; ++e)
#pragma unroll
        for (int m = 0; m < 4; ++m)
            asm volatile("" : "+v"(Wp[e][m][0]), "+v"(Wp[e][m][1]));

    // LDS byte offsets of the 4 swizzled float4 reads (within one h buffer).
    int lds_off[4];
#pragma unroll
    for (int e = 0; e < 4; ++e) lds_off[e] = kg * 64 + ((e + rot) & 3) * 16;

    const int  mycol = c0 + ((kg >> 2) & 3);   // column this lane finalizes
    const bool wr    = (kg & 3) == 0;          // 1 of 4 dup lanes writes

    if (tid < HID) hbuf[0][tid] = 0.f;

    const int* brow = batch + (size_t)b * T_LEN;
    int tok_n = brow[0];
    float axv = ax_tab[(size_t)tok_n * HID + mycol];   // ax for t=0
    tok_n = brow[1];
    __syncthreads();

#define RNN_STEP(CUR, NXT, TT)                                              \
    {                                                                       \
        const int tok_nn = ((TT) + 2 < T_LEN) ? brow[(TT) + 2] : 0;         \
        const float ax_n = ax_tab[(size_t)tok_n * HID + mycol];             \
        float2 a01, a23;                                                    \
        const char* hb = (const char*)&hbuf[CUR][0];                        \
        {   /* e = 0: first pk is a mul (inits acc) */                      \
            const float4 h4 = *(const float4*)(hb + lds_off[0]);            \
            const float2 hm01 = make_float2(h4.x, h4.y);                    \
            const float2 hm23 = make_float2(h4.z, h4.w);                    \
            PKMUL_LO(a01, hm01, Wp[0][0][0]);                               \
            PKMUL_LO(a23, hm01, Wp[0][0][1]);                               \
            PKFMA_HI(a01, hm01, Wp[0][1][0]);                               \
            PKFMA_HI(a23, hm01, Wp[0][1][1]);                               \
            PKFMA_LO(a01, hm23, Wp[0][2][0]);                               \
            PKFMA_LO(a23, hm23, Wp[0][2][1]);                               \
            PKFMA_HI(a01, hm23, Wp[0][3][0]);                               \
            PKFMA_HI(a23, hm23, Wp[0][3][1]);                               \
        }                                                                   \
        _Pragma("unroll")                                                   \
        for (int e = 1; e < 4; ++e) {                                       \
            const float4 h4 = *(const float4*)(hb + lds_off[e]);            \
            const float2 hm01 = make_float2(h4.x, h4.y);                    \
            const float2 hm23 = make_float2(h4.z, h4.w);                    \
            PKFMA_LO(a01, hm01, Wp[e][0][0]);                               \
            PKFMA_LO(a23, hm01, Wp[e][0][1]);                               \
            PKFMA_HI(a01, hm01, Wp[e][1][0]);                               \
            PKFMA_HI(a23, hm01, Wp[e][1][1]);                               \
            PKFMA_LO(a01, hm23, Wp[e][2][0]);                               \
            PKFMA_LO(a23, hm23, Wp[e][2][1]);                               \
            PKFMA_HI(a01, hm23, Wp[e][3][0]);                               \
            PKFMA_HI(a23, hm23, Wp[e][3][1]);                               \
        }                                                                   \
        float acc[4] = {a01.x, a01.y, a23.x, a23.y};                        \
        /* sel-pair halving tree over the 16 kg lanes */                    \
        _Pragma("unroll")                                                   \
        for (int i = 0; i < 2; ++i) {              /* mask 8: 4 -> 2 */     \
            const float send = (kg & 8) ? acc[i] : acc[i + 2];              \
            const float keep = (kg & 8) ? acc[i + 2] : acc[i];              \
            acc[i] = keep + __shfl_xor(send, 8);                            \
        }                                                                   \
        {                                          /* mask 4: 2 -> 1 */     \
            const float send = (kg & 4) ? acc[0] : acc[1];                  \
            const float keep = (kg & 4) ? acc[1] : acc[0];                  \
            acc[0] = keep + __shfl_xor(send, 4);                            \
        }                                                                   \
        acc[0] += __shfl_xor(acc[0], 2);           /* mask 2 */             \
        acc[0] += __shfl_xor(acc[0], 1);           /* mask 1 */             \
        const float hnew = fast_tanh(acc[0] + axv);                         \
        if (wr) hbuf[NXT][mycol] = hnew;                                    \
        __syncthreads();                                                    \
        axv   = ax_n;                                                       \
        tok_n = tok_nn;                                                     \
    }

    for (int t = 0; t < T_LEN; t += 2) {
        RNN_STEP(0, 1, t)
        RNN_STEP(1, 0, t + 1)
    }
#undef RNN_STEP

    // --- epilogue: out[b][c] = sum_j h[j] * clf_w[j][c] + clf_b[c] ---
    // After an even number of steps the final h is in hbuf[0].
    if (tid < HID) {
        const float h = hbuf[0][tid];
        sbuf[0][tid] = h * clfw[tid * N_CLS + 0];
        sbuf[1][tid] = h * clfw[tid * N_CLS + 1];
    }
    __syncthreads();
    if (tid < 64) {
        float v = sbuf[0][tid] + sbuf[0][tid + 64] +
                  sbuf[0][tid + 128] + sbuf[0][tid + 192];
#pragma unroll
        for (int off = 32; off > 0; off >>= 1) v += __shfl_xor(v, off);
        if (tid == 0) out[b * N_CLS + 0] = v + clfb[0];
    } else if (tid < 128) {
        const int l = tid - 64;
        float v = sbuf[1][l] + sbuf[1][l + 64] +
                  sbuf[1][l + 128] + sbuf[1][l + 192];
#pragma unroll
        for (int off = 32; off > 0; off >>= 1) v += __shfl_xor(v, off);
        if (l == 0) out[b * N_CLS + 1] = v + clfb[1];
    }
}

// ---------------------------------------------------------------------------
// Fallback (workspace too small for the 51.5 MB table).
// ---------------------------------------------------------------------------
__global__ __launch_bounds__(512, 2)
void rnn_fallback_kernel(const int*   __restrict__ batch,
                         const float* __restrict__ emb,
                         const float* __restrict__ wxw,
                         const float* __restrict__ wxb,
                         const float* __restrict__ whw,
                         const float* __restrict__ whb,
                         const float* __restrict__ clfw,
                         const float* __restrict__ clfb,
                         float*       __restrict__ out)
{
    const int b    = blockIdx.x;
    const int tid  = threadIdx.x;
    const int j    = tid >> 1;
    const int half = tid & 1;
    const int k0   = half * 128;

    __shared__ float hbuf[2][HID];
    __shared__ float ebuf[2][D_EMB];

    float w[128];
#pragma unroll
    for (int k = 0; k < 128; ++k)
        w[k] = whw[(size_t)(k0 + k) * HID + j];

    float wx[64];
#pragma unroll
    for (int d = 0; d < 64; ++d)
        wx[d] = wxw[(size_t)(half * 64 + d) * HID + j];

    const float bj  = whb[j];
    const float axb = wxb[j];

    if (tid < HID) hbuf[0][tid] = 0.f;

    const int* brow = batch + (size_t)b * T_LEN;

    int tok_n = brow[0];
    if (tid < D_EMB) ebuf[0][tid] = emb[(size_t)tok_n * D_EMB + tid];
    tok_n = brow[1];
    __syncthreads();

    float h_j = 0.f;
    int cur = 0;
    for (int t = 0; t < T_LEN; ++t) {
        const int nxt = cur ^ 1;
        const int tok_nn = (t + 2 < T_LEN) ? brow[t + 2] : 0;
        float ev = 0.f;
        if (t + 1 < T_LEN && tid < D_EMB)
            ev = emb[(size_t)tok_n * D_EMB + tid];

        float a0 = 0.f, a1 = 0.f, a2 = 0.f, a3 = 0.f;
        const float4* hv = (const float4*)&hbuf[cur][k0];
#pragma unroll
        for (int i = 0; i < 32; ++i) {
            float4 h4 = hv[i];
            a0 = fmaf(h4.x, w[4 * i + 0], a0);
            a1 = fmaf(h4.y, w[4 * i + 1], a1);
            a2 = fmaf(h4.z, w[4 * i + 2], a2);
            a3 = fmaf(h4.w, w[4 * i + 3], a3);
        }
        const float4* evv = (const float4*)&ebuf[cur][half * 64];
#pragma unroll
        for (int i = 0; i < 16; ++i) {
            float4 e4 = evv[i];
            a0 = fmaf(e4.x, wx[4 * i + 0], a0);
            a1 = fmaf(e4.y, wx[4 * i + 1], a1);
            a2 = fmaf(e4.z, wx[4 * i + 2], a2);
            a3 = fmaf(e4.w, wx[4 * i + 3], a3);
        }
        float s = (a0 + a1) + (a2 + a3);
        s += __shfl_xor(s, 1);

        h_j = fast_tanh(s + bj + axb);

        if (half == 0) hbuf[nxt][j] = h_j;
        if (t + 1 < T_LEN && tid < D_EMB) ebuf[nxt][tid] = ev;
        __syncthreads();

        tok_n = tok_nn;
        cur   = nxt;
    }

    if (half == 0) {
        hbuf[0][j] = h_j * clfw[j * N_CLS + 0];
        hbuf[1][j] = h_j * clfw[j * N_CLS + 1];
    }
    __syncthreads();
    if (tid < 64) {
        float v = hbuf[0][tid] + hbuf[0][tid + 64] +
                  hbuf[0][tid + 128] + hbuf[0][tid + 192];
#pragma unroll
        for (int off = 32; off > 0; off >>= 1) v += __shfl_xor(v, off);
        if (tid == 0) out[b * N_CLS + 0] = v + clfb[0];
    } else if (tid < 128) {
        const int l = tid - 64;
        float v = hbuf[1][l] + hbuf[1][l + 64] +
                  hbuf[1][l + 128] + hbuf[1][l + 192];
#pragma unroll
        for (int off = 32; off > 0; off >>= 1) v += __shfl_xor(v, off);
        if (l == 0) out[b * N_CLS + 1] = v + clfb[1];
    }
}

// ---------------------------------------------------------------------------
extern "C" void kernel_launch(void* const* d_in, const int* in_sizes, int n_in,
                              void* d_out, int out_size, void* d_ws, size_t ws_size,
                              hipStream_t stream)
{
    const int*   batch = (const int*)  d_in[0];
    const float* emb   = (const float*)d_in[1];
    const float* wxw   = (const float*)d_in[2];
    const float* wxb   = (const float*)d_in[3];
    const float* whw   = (const float*)d_in[4];
    const float* whb   = (const float*)d_in[5];
    const float* clfw  = (const float*)d_in[6];
    const float* clfb  = (const float*)d_in[7];
    float* out = (float*)d_out;

    const size_t tab_bytes = (size_t)VOCAB * HID * sizeof(float);
    if (ws_size >= tab_bytes) {
        float* tab = (float*)d_ws;
        tabax_kernel<<<(VOCAB + 31) / 32, 256, 0, stream>>>(emb, wxw, wxb, whb, tab);
        rnn_main_kernel<<<BSZ, 1024, 0, stream>>>(batch, whw, clfw, clfb, tab, out);
    } else {
        rnn_fallback_kernel<<<BSZ, 512, 0, stream>>>(batch, emb, wxw, wxb, whw, whb,
                                                     clfw, clfb, out);
    }
}